// Round 11
// baseline (1630.690 us; speedup 1.0000x reference)
//
#include <hip/hip_runtime.h>
#include <cmath>
#include <cstring>
#include <complex>

#define HCH 32

// ---------------- CG tables (computed on host, passed by value) ----------------
struct CGT {
  float c000;      // CG[0,0,0]
  float c011[9];   // [b*3+c]
  float c101[9];   // [a*3+c]
  float c110[9];   // [a*3+b]  (c=0)
  float c111[27];  // [(a*3+b)*3+c]
  float c121[45];  // [(a*5+b)*3+c]
  float dk[9];     // exp(-50(2k-1)/81), k=1..9  (radial-basis recurrence ratios)
};

static double factd(int n){ double r=1.0; for(int i=2;i<=n;++i) r*=i; return r; }

static double cg1(int l1,int m1,int l2,int m2,int l3,int m3){
  if(m1+m2!=m3) return 0.0;
  double pref = std::sqrt((2*l3+1)*factd(l3+l1-l2)*factd(l3-l1+l2)*factd(l1+l2-l3)/factd(l1+l2+l3+1));
  pref *= std::sqrt(factd(l3+m3)*factd(l3-m3)*factd(l1-m1)*factd(l1+m1)*factd(l2-m2)*factd(l2+m2));
  double s=0.0;
  for(int k=0;k<=l1+l2-l3;++k){
    int d[6]={k, l1+l2-l3-k, l1-m1-k, l2+m2-k, l3-l2+m1+k, l3-l1-m2+k};
    bool neg=false; for(int i=0;i<6;i++) if(d[i]<0) neg=true;
    if(neg) continue;
    double prod=1.0; for(int i=0;i<6;i++) prod*=factd(d[i]);
    s += ((k&1)? -1.0:1.0)/prod;
  }
  return pref*s;
}

static void qmat(int l, std::complex<double> Q[5][5]){
  for(int i=0;i<5;i++) for(int j=0;j<5;j++) Q[i][j]=0.0;
  Q[l][l]=1.0;
  const double is2 = 1.0/std::sqrt(2.0);
  for(int m=1;m<=l;m++){
    double sgn = (m&1)? -1.0: 1.0;
    Q[l+m][l+m] = sgn*is2;
    Q[l+m][l-m] = is2;
    Q[l-m][l-m] = std::complex<double>(0.0, is2);
    Q[l-m][l+m] = std::complex<double>(0.0, -sgn*is2);
  }
}

static void real_cg(int l1,int l2,int l3, float* out){
  int n1=2*l1+1, n2=2*l2+1, n3=2*l3+1;
  double Cc[5][5][5];
  std::memset(Cc,0,sizeof Cc);
  for(int m1=-l1;m1<=l1;m1++) for(int m2=-l2;m2<=l2;m2++){
    int m3=m1+m2;
    if(m3>=-l3 && m3<=l3) Cc[m1+l1][m2+l2][m3+l3]=cg1(l1,m1,l2,m2,l3,m3);
  }
  std::complex<double> Q1[5][5],Q2[5][5],Q3[5][5];
  qmat(l1,Q1); qmat(l2,Q2); qmat(l3,Q3);
  std::complex<double> C[5][5][5];
  double maxre=0.0, maxim=0.0;
  for(int a=0;a<n1;a++) for(int b=0;b<n2;b++) for(int c=0;c<n3;c++){
    std::complex<double> s=0.0;
    for(int i=0;i<n1;i++) for(int j=0;j<n2;j++) for(int k=0;k<n3;k++){
      double cc=Cc[i][j][k];
      if(cc!=0.0) s += Q1[a][i]*Q2[b][j]*std::conj(Q3[c][k])*cc;
    }
    C[a][b][c]=s;
    maxre=std::max(maxre,std::fabs(s.real()));
    maxim=std::max(maxim,std::fabs(s.imag()));
  }
  bool flip = maxim>maxre;
  for(int a=0;a<n1;a++) for(int b=0;b<n2;b++) for(int c=0;c<n3;c++){
    std::complex<double> v=C[a][b][c];
    if(flip) v *= std::complex<double>(0.0,-1.0);
    out[(a*n2+b)*n3+c]=(float)v.real();
  }
}

static void build_cg(CGT* cg){
  float t000[1];  real_cg(0,0,0,t000); cg->c000=t000[0];
  real_cg(0,1,1,cg->c011);
  real_cg(1,0,1,cg->c101);
  real_cg(1,1,0,cg->c110);
  real_cg(1,1,1,cg->c111);
  real_cg(1,2,1,cg->c121);
  for(int k=1;k<=9;k++) cg->dk[k-1] = (float)std::exp(-50.0*(2.0*k-1.0)/81.0);
}

// ---------------- device helpers ----------------
__device__ __forceinline__ float sspf(float x){
  return fmaxf(x,0.0f) + __logf(1.0f + __expf(-fabsf(x))) - 0.69314718055994530942f;
}

// radial basis via geometric recurrence: emb[k] = e0 * q^k * c_k,
// e0 = exp(-50(d-0.7)^2), q = exp((100d-70)/9), c_k/c_{k-1} = dk[k-1] (host-computed).
// 2 transcendentals instead of 10.
__device__ __forceinline__ float edge_env_rec(float d, float* emb, const float* __restrict__ dk){
  float t0 = d - 0.7f;
  float e0 = __expf(-50.f*t0*t0);
  float q  = __expf((100.f*d - 70.f)*(1.f/9.f));
  emb[0] = e0;
  float cur = e0;
#pragma unroll
  for(int k=1;k<10;k++){ cur *= q*dk[k-1]; emb[k] = cur; }
  float u = d*(1.0f/1.5f);
  if(u >= 1.0f) return 0.0f;
  float u2=u*u, u3=u2*u, u6=u3*u3, u7=u6*u, u8=u7*u;
  return 1.0f - 28.0f*u6 + 48.0f*u7 - 21.0f*u8;
}

__device__ __forceinline__ float edge_env_inline(float d, float* emb){
#pragma unroll
  for(int k=0;k<10;k++){
    float t = d - (0.7f + (float)k*(1.0f/9.0f));
    emb[k] = __expf(-t*t*50.0f);
  }
  float u = d*(1.0f/1.5f);
  if(u >= 1.0f) return 0.0f;
  float u2=u*u, u3=u2*u, u6=u3*u3, u7=u6*u, u8=u7*u;
  return 1.0f - 28.0f*u6 + 48.0f*u7 - 21.0f*u8;
}

// ================= CSR build =================
__global__ void deg_kernel(const int* __restrict__ ei, int* __restrict__ deg, int E){
  int e = blockIdx.x*blockDim.x + threadIdx.x;
  if(e >= E) return;
  atomicAdd(&deg[ei[E+e]], 1);
}

__global__ void scanA_kernel(const int* __restrict__ deg, int* __restrict__ rowptr,
                             int* __restrict__ bsum, int N){
  __shared__ int sm[256];
  int t = threadIdx.x, b = blockIdx.x, i = b*256 + t;
  int v = (i < N) ? deg[i] : 0;
  sm[t] = v;
  __syncthreads();
  for(int off=1; off<256; off<<=1){
    int add = (t >= off) ? sm[t-off] : 0;
    __syncthreads();
    sm[t] += add;
    __syncthreads();
  }
  if(i < N) rowptr[i] = sm[t] - v;
  if(t == 255) bsum[b] = sm[255];
}

__global__ void scanB_kernel(int* __restrict__ bsum, int* __restrict__ rowptr, int nb, int N){
  __shared__ int sm[256];
  int t = threadIdx.x;
  int v = (t < nb) ? bsum[t] : 0;
  sm[t] = v;
  __syncthreads();
  for(int off=1; off<256; off<<=1){
    int add = (t >= off) ? sm[t-off] : 0;
    __syncthreads();
    sm[t] += add;
    __syncthreads();
  }
  if(t < nb) bsum[t] = sm[t] - v;
  if(t == 255) rowptr[N] = sm[255];
}

__global__ void scanC_kernel(int* __restrict__ rowptr, const int* __restrict__ bsum, int N){
  int i = blockIdx.x*blockDim.x + threadIdx.x;
  if(i < N) rowptr[i] += bsum[i>>8];
}

// record (3 float4 = 48B): {elen,src,sh0,sh1}{sh2..5}{sh6,sh7,sh8,0}
__global__ void fill_kernel(const int* __restrict__ ei, const float* __restrict__ elen,
                            const float* __restrict__ sh,
                            const int* __restrict__ rowptr, int* __restrict__ fillc,
                            float* __restrict__ pedge, int E){
  int e = blockIdx.x*blockDim.x + threadIdx.x;
  if(e >= E) return;
  int dst = ei[E+e];
  int p = atomicAdd(&fillc[dst], 1);
  size_t slot = (size_t)rowptr[dst] + p;
  const float* she = sh + (size_t)e*9;
  float4* pd = (float4*)pedge + slot*3;
  pd[0] = make_float4(elen[e], __int_as_float(ei[e]), she[0], she[1]);
  pd[1] = make_float4(she[2], she[3], she[4], she[5]);
  pd[2] = make_float4(she[6], she[7], she[8], 0.f);
}

// ================= gather layers (thread per (node,h); r5 structure + rec-emb + unroll2) =================

__global__ __launch_bounds__(256, 4)
void g1_kernel(const float* __restrict__ x,
               const float* __restrict__ pedge,
               const int* __restrict__ rowptr,
               const float* __restrict__ W1, const float* __restrict__ b1,
               float* __restrict__ out, int N, CGT cg){
  int t = blockIdx.x*blockDim.x + threadIdx.x;
  int n = t >> 5, h = t & 31;
  if(n >= N) return;
  int beg = rowptr[n], end = rowptr[n+1];
  float bb0 = b1[h], bb1 = b1[HCH+h];
  float a0=0.f, a1=0.f, a2=0.f, a3=0.f;
  const float4* pe = (const float4*)pedge;
#pragma unroll 2
  for(int i=beg;i<end;i++){
    float4 r0 = pe[(size_t)i*3+0];
    float4 r1 = pe[(size_t)i*3+1];
    float em[10];
    float ew = edge_env_rec(r0.x, em, cg.dk);
    int src = __float_as_int(r0.y);
    float w0 = bb0, w1v = bb1;
#pragma unroll
    for(int k=0;k<10;k++){
      w0  += em[k]*W1[k*64 + h];
      w1v += em[k]*W1[k*64 + HCH + h];
    }
    float base = x[src]*ew;
    a0 += cg.c000*base*r0.z*w0;
    float bw = base*w1v;
    a1 += (cg.c011[0]*r0.w + cg.c011[3]*r1.x + cg.c011[6]*r1.y)*bw;
    a2 += (cg.c011[1]*r0.w + cg.c011[4]*r1.x + cg.c011[7]*r1.y)*bw;
    a3 += (cg.c011[2]*r0.w + cg.c011[5]*r1.x + cg.c011[8]*r1.y)*bw;
  }
  float ss = a1*a1 + a2*a2 + a3*a3 + 1e-12f;
  float rn = rsqrtf(ss);
  float sc = sspf(ss*rn)*rn;
  float* p = out + (size_t)n*128;
  p[h]       = sspf(a0);
  p[HCH+h]   = a1*sc;
  p[2*HCH+h] = a2*sc;
  p[3*HCH+h] = a3*sc;
}

__global__ __launch_bounds__(256, 4)
void g2_kernel(const float* __restrict__ hin,
               const float* __restrict__ pedge,
               const int* __restrict__ rowptr,
               const float* __restrict__ W2, const float* __restrict__ b2,
               float* __restrict__ out, int N, CGT cg){
  int t = blockIdx.x*blockDim.x + threadIdx.x;
  int n = t >> 5, h = t & 31;
  if(n >= N) return;
  int beg = rowptr[n], end = rowptr[n+1];
  float bb[6];
#pragma unroll
  for(int p=0;p<6;p++) bb[p] = b2[p*HCH + h];
  float a0=0.f, a1=0.f, a2=0.f, a3=0.f;
  const float4* pe = (const float4*)pedge;
#pragma unroll 2
  for(int i=beg;i<end;i++){
    float4 r0 = pe[(size_t)i*3+0];
    float4 r1 = pe[(size_t)i*3+1];
    float4 r2 = pe[(size_t)i*3+2];
    float em[10];
    float ew = edge_env_rec(r0.x, em, cg.dk);
    int src = __float_as_int(r0.y);
    float w_[6];
#pragma unroll
    for(int p=0;p<6;p++) w_[p] = bb[p];
#pragma unroll
    for(int k=0;k<10;k++)
#pragma unroll
      for(int p=0;p<6;p++) w_[p] += em[k]*W2[k*192 + p*HCH + h];
    const float* hn = hin + (size_t)src*128;
    float x0  = hn[h];
    float xv0 = hn[HCH+h], xv1 = hn[2*HCH+h], xv2 = hn[3*HCH+h];
    float s0  = r0.z;
    float sv0 = r0.w, sv1 = r1.x, sv2 = r1.y;
    float s2v[5] = { r1.z, r1.w, r2.x, r2.y, r2.z };

    float m0 = 0.0f, m1 = 0.0f, m2 = 0.0f, m3 = 0.0f;
    m0 += cg.c000 * x0 * s0 * w_[0];
    {
      float xw = x0 * w_[1];
      m1 += (cg.c011[0]*sv0 + cg.c011[3]*sv1 + cg.c011[6]*sv2)*xw;
      m2 += (cg.c011[1]*sv0 + cg.c011[4]*sv1 + cg.c011[7]*sv2)*xw;
      m3 += (cg.c011[2]*sv0 + cg.c011[5]*sv1 + cg.c011[8]*sv2)*xw;
    }
    {
      float sw = s0 * w_[2];
      m1 += (cg.c101[0]*xv0 + cg.c101[3]*xv1 + cg.c101[6]*xv2)*sw;
      m2 += (cg.c101[1]*xv0 + cg.c101[4]*xv1 + cg.c101[7]*xv2)*sw;
      m3 += (cg.c101[2]*xv0 + cg.c101[5]*xv1 + cg.c101[8]*xv2)*sw;
    }
    {
      float tt = cg.c110[0]*xv0*sv0 + cg.c110[1]*xv0*sv1 + cg.c110[2]*xv0*sv2
               + cg.c110[3]*xv1*sv0 + cg.c110[4]*xv1*sv1 + cg.c110[5]*xv1*sv2
               + cg.c110[6]*xv2*sv0 + cg.c110[7]*xv2*sv1 + cg.c110[8]*xv2*sv2;
      m0 += tt * w_[3];
    }
    {
      float xvv[3] = {xv0, xv1, xv2};
      float svv[3] = {sv0, sv1, sv2};
      float t1=0.f, t2=0.f, t3=0.f;
#pragma unroll
      for(int a=0;a<3;a++)
#pragma unroll
        for(int b=0;b<3;b++){
          float xs = xvv[a]*svv[b];
          t1 += cg.c111[(a*3+b)*3+0]*xs;
          t2 += cg.c111[(a*3+b)*3+1]*xs;
          t3 += cg.c111[(a*3+b)*3+2]*xs;
        }
      m1 += t1*w_[4]; m2 += t2*w_[4]; m3 += t3*w_[4];
    }
    {
      float xvv[3] = {xv0, xv1, xv2};
      float t1=0.f, t2=0.f, t3=0.f;
#pragma unroll
      for(int a=0;a<3;a++)
#pragma unroll
        for(int b=0;b<5;b++){
          float xs = xvv[a]*s2v[b];
          t1 += cg.c121[(a*5+b)*3+0]*xs;
          t2 += cg.c121[(a*5+b)*3+1]*xs;
          t3 += cg.c121[(a*5+b)*3+2]*xs;
        }
      m1 += t1*w_[5]; m2 += t2*w_[5]; m3 += t3*w_[5];
    }
    a0 += m0*ew; a1 += m1*ew; a2 += m2*ew; a3 += m3*ew;
  }
  float ss = a1*a1 + a2*a2 + a3*a3 + 1e-12f;
  float rn = rsqrtf(ss);
  float sc = sspf(ss*rn)*rn;
  float* p = out + (size_t)n*128;
  p[h]       = sspf(a0);
  p[HCH+h]   = a1*sc;
  p[2*HCH+h] = a2*sc;
  p[3*HCH+h] = a3*sc;
}

__global__ __launch_bounds__(256, 4)
void g3_kernel(const float* __restrict__ hin,
               const float* __restrict__ pedge,
               const int* __restrict__ rowptr,
               const int* __restrict__ batch,
               const float* __restrict__ W3, const float* __restrict__ b3,
               float* __restrict__ g, int N, CGT cg){
  int t = blockIdx.x*blockDim.x + threadIdx.x;
  int n = t >> 5, h = t & 31;
  if(n >= N) return;
  int beg = rowptr[n], end = rowptr[n+1];
  float bb0 = b3[h], bb1 = b3[HCH+h];
  float acc = 0.f;
  const float4* pe = (const float4*)pedge;
#pragma unroll 2
  for(int i=beg;i<end;i++){
    float4 r0 = pe[(size_t)i*3+0];
    float4 r1 = pe[(size_t)i*3+1];
    float em[10];
    float ew = edge_env_rec(r0.x, em, cg.dk);
    int src = __float_as_int(r0.y);
    float w0 = bb0, w1v = bb1;
#pragma unroll
    for(int k=0;k<10;k++){
      w0  += em[k]*W3[k*64 + h];
      w1v += em[k]*W3[k*64 + HCH + h];
    }
    const float* hn = hin + (size_t)src*128;
    float x0 = hn[h];
    float xv0 = hn[HCH+h], xv1 = hn[2*HCH+h], xv2 = hn[3*HCH+h];
    float m = cg.c000 * x0 * r0.z * w0;
    float tt = cg.c110[0]*xv0*r0.w + cg.c110[1]*xv0*r1.x + cg.c110[2]*xv0*r1.y
             + cg.c110[3]*xv1*r0.w + cg.c110[4]*xv1*r1.x + cg.c110[5]*xv1*r1.y
             + cg.c110[6]*xv2*r0.w + cg.c110[7]*xv2*r1.x + cg.c110[8]*xv2*r1.y;
    m += tt * w1v;
    acc += m*ew;
  }
  float si = acc*__frcp_rn(1.0f + __expf(-acc));
  atomicAdd(&g[(size_t)batch[n]*HCH + h], si);
}

// ================= fallback atomic-scatter layers =================
__global__ void l1_kernel(const float* __restrict__ x, const int* __restrict__ ei,
                          const float* __restrict__ sh, const float* __restrict__ elen,
                          const float* __restrict__ W1, const float* __restrict__ b1,
                          float* __restrict__ acc, int E, CGT cg){
  int t = blockIdx.x*blockDim.x + threadIdx.x;
  int e = t >> 5, h = t & 31;
  if(e >= E) return;
  float emb[10];
  float ew = edge_env_inline(elen[e], emb);
  int src = ei[e], dst = ei[E+e];
  float w0 = b1[h], w1v = b1[HCH+h];
#pragma unroll
  for(int k=0;k<10;k++){
    w0  += emb[k]*W1[k*64 + h];
    w1v += emb[k]*W1[k*64 + HCH + h];
  }
  const float* she = sh + (size_t)e*9;
  float base = x[src]*ew;
  float* ad = acc + (size_t)dst*128;
  atomicAdd(&ad[h], cg.c000*base*she[0]*w0);
  float bw = base*w1v;
  atomicAdd(&ad[HCH+h],   (cg.c011[0]*she[1] + cg.c011[3]*she[2] + cg.c011[6]*she[3])*bw);
  atomicAdd(&ad[2*HCH+h], (cg.c011[1]*she[1] + cg.c011[4]*she[2] + cg.c011[7]*she[3])*bw);
  atomicAdd(&ad[3*HCH+h], (cg.c011[2]*she[1] + cg.c011[5]*she[2] + cg.c011[8]*she[3])*bw);
}

__global__ void normact_kernel(float* __restrict__ buf, int N){
  int t = blockIdx.x*blockDim.x + threadIdx.x;
  int n = t >> 5, h = t & 31;
  if(n >= N) return;
  float* p = buf + (size_t)n*128;
  float s  = p[h];
  float v1 = p[HCH+h], v2 = p[2*HCH+h], v3 = p[3*HCH+h];
  float ss = v1*v1 + v2*v2 + v3*v3 + 1e-12f;
  float rn = rsqrtf(ss);
  float sc = sspf(ss*rn)*rn;
  p[h]       = sspf(s);
  p[HCH+h]   = v1*sc;
  p[2*HCH+h] = v2*sc;
  p[3*HCH+h] = v3*sc;
}

__global__ void l2_kernel(const float* __restrict__ hin, const int* __restrict__ ei,
                          const float* __restrict__ sh, const float* __restrict__ elen,
                          const float* __restrict__ W2, const float* __restrict__ b2,
                          float* __restrict__ acc, int E, CGT cg){
  int t = blockIdx.x*blockDim.x + threadIdx.x;
  int e = t >> 5, h = t & 31;
  if(e >= E) return;
  float emb[10];
  float ew = edge_env_inline(elen[e], emb);
  int src = ei[e], dst = ei[E+e];
  float w[6];
#pragma unroll
  for(int p=0;p<6;p++) w[p] = b2[p*HCH + h];
#pragma unroll
  for(int k=0;k<10;k++){
    float ek = emb[k];
    const float* Wr = W2 + k*192;
#pragma unroll
    for(int p=0;p<6;p++) w[p] += ek*Wr[p*HCH + h];
  }
  const float* hn = hin + (size_t)src*128;
  float x0 = hn[h];
  float xv[3] = { hn[HCH+h], hn[2*HCH+h], hn[3*HCH+h] };
  const float* she = sh + (size_t)e*9;
  float s0 = she[0];
  float sv[3]  = { she[1], she[2], she[3] };
  float s2v[5] = { she[4], she[5], she[6], she[7], she[8] };
  float m0 = 0.0f, m[3] = {0.0f,0.0f,0.0f};
  m0 += cg.c000 * x0 * s0 * w[0];
#pragma unroll
  for(int c=0;c<3;c++){
    float tc = cg.c011[0*3+c]*sv[0] + cg.c011[1*3+c]*sv[1] + cg.c011[2*3+c]*sv[2];
    m[c] += tc * x0 * w[1];
  }
#pragma unroll
  for(int c=0;c<3;c++){
    float tc = cg.c101[0*3+c]*xv[0] + cg.c101[1*3+c]*xv[1] + cg.c101[2*3+c]*xv[2];
    m[c] += tc * s0 * w[2];
  }
  {
    float tt=0.0f;
#pragma unroll
    for(int a=0;a<3;a++)
#pragma unroll
      for(int b=0;b<3;b++) tt += cg.c110[a*3+b]*xv[a]*sv[b];
    m0 += tt * w[3];
  }
#pragma unroll
  for(int c=0;c<3;c++){
    float tt=0.0f;
#pragma unroll
    for(int a=0;a<3;a++)
#pragma unroll
      for(int b=0;b<3;b++) tt += cg.c111[(a*3+b)*3+c]*xv[a]*sv[b];
    m[c] += tt * w[4];
  }
#pragma unroll
  for(int c=0;c<3;c++){
    float tt=0.0f;
#pragma unroll
    for(int a=0;a<3;a++)
#pragma unroll
      for(int b=0;b<5;b++) tt += cg.c121[(a*5+b)*3+c]*xv[a]*s2v[b];
    m[c] += tt * w[5];
  }
  float* ad = acc + (size_t)dst*128;
  atomicAdd(&ad[h], m0*ew);
#pragma unroll
  for(int c=0;c<3;c++) atomicAdd(&ad[(1+c)*HCH + h], m[c]*ew);
}

__global__ void l3_kernel(const float* __restrict__ hin, const int* __restrict__ ei,
                          const float* __restrict__ sh, const float* __restrict__ elen,
                          const float* __restrict__ W3, const float* __restrict__ b3,
                          float* __restrict__ acc, int E, CGT cg){
  int t = blockIdx.x*blockDim.x + threadIdx.x;
  int e = t >> 5, h = t & 31;
  if(e >= E) return;
  float emb[10];
  float ew = edge_env_inline(elen[e], emb);
  int src = ei[e], dst = ei[E+e];
  float w0 = b3[h], w1v = b3[HCH+h];
#pragma unroll
  for(int k=0;k<10;k++){
    w0  += emb[k]*W3[k*64 + h];
    w1v += emb[k]*W3[k*64 + HCH + h];
  }
  const float* hn = hin + (size_t)src*128;
  float x0 = hn[h];
  float xv[3] = { hn[HCH+h], hn[2*HCH+h], hn[3*HCH+h] };
  const float* she = sh + (size_t)e*9;
  float m = cg.c000 * x0 * she[0] * w0;
  float tt = cg.c110[0]*xv[0]*she[1] + cg.c110[1]*xv[0]*she[2] + cg.c110[2]*xv[0]*she[3]
           + cg.c110[3]*xv[1]*she[1] + cg.c110[4]*xv[1]*she[2] + cg.c110[5]*xv[1]*she[3]
           + cg.c110[6]*xv[2]*she[1] + cg.c110[7]*xv[2]*she[2] + cg.c110[8]*xv[2]*she[3];
  m += tt * w1v;
  atomicAdd(&acc[(size_t)dst*HCH + h], m*ew);
}

__global__ void pool_kernel(const float* __restrict__ acc, const int* __restrict__ batch,
                            float* __restrict__ g, int N){
  int t = blockIdx.x*blockDim.x + threadIdx.x;
  int n = t >> 5, h = t & 31;
  if(n >= N) return;
  float v = acc[(size_t)n*HCH + h];
  float si = v*__frcp_rn(1.0f + __expf(-v));
  atomicAdd(&g[(size_t)batch[n]*HCH + h], si);
}

// ---------------- head ----------------
__global__ void head_kernel(const float* __restrict__ g, const float* __restrict__ Wo,
                            const float* __restrict__ bo, float* __restrict__ out){
  int gi = threadIdx.x;
  if(gi >= 128) return;
  float logit[8];
#pragma unroll
  for(int o=0;o<8;o++) logit[o] = bo[o];
  for(int hh=0; hh<HCH; hh++){
    float gv = g[gi*HCH + hh];
#pragma unroll
    for(int o=0;o<8;o++) logit[o] += gv*Wo[hh*8 + o];
  }
  float mx = logit[0];
#pragma unroll
  for(int o=1;o<8;o++) mx = fmaxf(mx, logit[o]);
  float ex[8]; float s=0.0f;
#pragma unroll
  for(int o=0;o<8;o++){ ex[o]=__expf(logit[o]-mx); s+=ex[o]; }
  float inv = 1.0f/s;
#pragma unroll
  for(int o=0;o<8;o++) out[gi*8 + o] = ex[o]*inv;
}

extern "C" void kernel_launch(void* const* d_in, const int* in_sizes, int n_in,
                              void* d_out, int out_size, void* d_ws, size_t ws_size,
                              hipStream_t stream){
  const float* x    = (const float*)d_in[0];
  const int*   ei   = (const int*)  d_in[1];
  const float* sh   = (const float*)d_in[2];
  const float* elen = (const float*)d_in[3];
  const int*   batch= (const int*)  d_in[4];
  const float* W1   = (const float*)d_in[5];
  const float* b1   = (const float*)d_in[6];
  const float* W2   = (const float*)d_in[7];
  const float* b2   = (const float*)d_in[8];
  const float* W3   = (const float*)d_in[9];
  const float* b3   = (const float*)d_in[10];
  const float* Wo   = (const float*)d_in[11];
  const float* bo   = (const float*)d_in[12];
  int N = in_sizes[0];
  int E = in_sizes[3];

  CGT cg; build_cg(&cg);

  int nb = (N + 255)/256;

  // CSR-path workspace layout
  float* pedge  = (float*)d_ws;                    // E*12 floats (48B records)
  float* bufA   = pedge + (size_t)E*12;            // N*128
  float* bufB   = bufA + (size_t)N*128;            // N*128
  float* g      = bufB + (size_t)N*128;            // 128*32
  int*   deg    = (int*)(g + 128*HCH);             // N
  int*   fillc  = deg + N;                         // N
  int*   rowptr = fillc + N;                       // N+1
  int*   bsum   = rowptr + (N+1);                  // <=256

  size_t csr_b = ((size_t)E*12 + (size_t)N*128*2 + 128*HCH)*sizeof(float)
               + ((size_t)3*N + 1 + 256)*sizeof(int);
  bool use_csr = (ws_size >= csr_b) && (nb <= 256);

  dim3 blk(256);
  int eblk1   = (E + 255)/256;
  int eblocks = (int)(((long long)E*HCH + 255)/256);
  int nblocks = (int)(((long long)N*HCH + 255)/256);

  if(use_csr){
    hipMemsetAsync(g, 0, (size_t)(128*HCH)*sizeof(float) + (size_t)2*N*sizeof(int), stream);
    deg_kernel <<<eblk1, blk, 0, stream>>>(ei, deg, E);
    scanA_kernel<<<nb, blk, 0, stream>>>(deg, rowptr, bsum, N);
    scanB_kernel<<<1, blk, 0, stream>>>(bsum, rowptr, nb, N);
    scanC_kernel<<<nb, blk, 0, stream>>>(rowptr, bsum, N);
    fill_kernel<<<eblk1, blk, 0, stream>>>(ei, elen, sh, rowptr, fillc, pedge, E);
    g1_kernel<<<nblocks, blk, 0, stream>>>(x, pedge, rowptr, W1, b1, bufA, N, cg);
    g2_kernel<<<nblocks, blk, 0, stream>>>(bufA, pedge, rowptr, W2, b2, bufB, N, cg);
    g3_kernel<<<nblocks, blk, 0, stream>>>(bufB, pedge, rowptr, batch, W3, b3, g, N, cg);
    head_kernel<<<1, 128, 0, stream>>>(g, Wo, bo, (float*)d_out);
  } else {
    float* fbufA = (float*)d_ws;
    float* fbufB = fbufA + (size_t)N*128;
    float* fbufC = fbufB + (size_t)N*128;
    float* fg    = fbufC + (size_t)N*HCH;
    size_t base_b = ((size_t)N*128*2 + (size_t)N*HCH + 128*HCH)*sizeof(float);
    hipMemsetAsync(d_ws, 0, base_b, stream);
    l1_kernel<<<eblocks, blk, 0, stream>>>(x, ei, sh, elen, W1, b1, fbufA, E, cg);
    normact_kernel<<<nblocks, blk, 0, stream>>>(fbufA, N);
    l2_kernel<<<eblocks, blk, 0, stream>>>(fbufA, ei, sh, elen, W2, b2, fbufB, E, cg);
    normact_kernel<<<nblocks, blk, 0, stream>>>(fbufB, N);
    l3_kernel<<<eblocks, blk, 0, stream>>>(fbufB, ei, sh, elen, W3, b3, fbufC, E, cg);
    pool_kernel<<<nblocks, blk, 0, stream>>>(fbufC, batch, fg, N);
    head_kernel<<<1, 128, 0, stream>>>(fg, Wo, bo, (float*)d_out);
  }
}

// Round 12
// 590.305 us; speedup vs baseline: 2.7625x; 2.7625x over previous
//
#include <hip/hip_runtime.h>
#include <cmath>
#include <cstring>
#include <complex>

#define HCH 32

// ---------------- CG tables (computed on host, passed by value) ----------------
struct CGT {
  float c000;      // CG[0,0,0]
  float c011[9];   // [b*3+c]
  float c101[9];   // [a*3+c]
  float c110[9];   // [a*3+b]  (c=0)
  float c111[27];  // [(a*3+b)*3+c]
  float c121[45];  // [(a*5+b)*3+c]
};

static double factd(int n){ double r=1.0; for(int i=2;i<=n;++i) r*=i; return r; }

static double cg1(int l1,int m1,int l2,int m2,int l3,int m3){
  if(m1+m2!=m3) return 0.0;
  double pref = std::sqrt((2*l3+1)*factd(l3+l1-l2)*factd(l3-l1+l2)*factd(l1+l2-l3)/factd(l1+l2+l3+1));
  pref *= std::sqrt(factd(l3+m3)*factd(l3-m3)*factd(l1-m1)*factd(l1+m1)*factd(l2-m2)*factd(l2+m2));
  double s=0.0;
  for(int k=0;k<=l1+l2-l3;++k){
    int d[6]={k, l1+l2-l3-k, l1-m1-k, l2+m2-k, l3-l2+m1+k, l3-l1-m2+k};
    bool neg=false; for(int i=0;i<6;i++) if(d[i]<0) neg=true;
    if(neg) continue;
    double prod=1.0; for(int i=0;i<6;i++) prod*=factd(d[i]);
    s += ((k&1)? -1.0:1.0)/prod;
  }
  return pref*s;
}

static void qmat(int l, std::complex<double> Q[5][5]){
  for(int i=0;i<5;i++) for(int j=0;j<5;j++) Q[i][j]=0.0;
  Q[l][l]=1.0;
  const double is2 = 1.0/std::sqrt(2.0);
  for(int m=1;m<=l;m++){
    double sgn = (m&1)? -1.0: 1.0;
    Q[l+m][l+m] = sgn*is2;
    Q[l+m][l-m] = is2;
    Q[l-m][l-m] = std::complex<double>(0.0, is2);
    Q[l-m][l+m] = std::complex<double>(0.0, -sgn*is2);
  }
}

static void real_cg(int l1,int l2,int l3, float* out){
  int n1=2*l1+1, n2=2*l2+1, n3=2*l3+1;
  double Cc[5][5][5];
  std::memset(Cc,0,sizeof Cc);
  for(int m1=-l1;m1<=l1;m1++) for(int m2=-l2;m2<=l2;m2++){
    int m3=m1+m2;
    if(m3>=-l3 && m3<=l3) Cc[m1+l1][m2+l2][m3+l3]=cg1(l1,m1,l2,m2,l3,m3);
  }
  std::complex<double> Q1[5][5],Q2[5][5],Q3[5][5];
  qmat(l1,Q1); qmat(l2,Q2); qmat(l3,Q3);
  std::complex<double> C[5][5][5];
  double maxre=0.0, maxim=0.0;
  for(int a=0;a<n1;a++) for(int b=0;b<n2;b++) for(int c=0;c<n3;c++){
    std::complex<double> s=0.0;
    for(int i=0;i<n1;i++) for(int j=0;j<n2;j++) for(int k=0;k<n3;k++){
      double cc=Cc[i][j][k];
      if(cc!=0.0) s += Q1[a][i]*Q2[b][j]*std::conj(Q3[c][k])*cc;
    }
    C[a][b][c]=s;
    maxre=std::max(maxre,std::fabs(s.real()));
    maxim=std::max(maxim,std::fabs(s.imag()));
  }
  bool flip = maxim>maxre;
  for(int a=0;a<n1;a++) for(int b=0;b<n2;b++) for(int c=0;c<n3;c++){
    std::complex<double> v=C[a][b][c];
    if(flip) v *= std::complex<double>(0.0,-1.0);
    out[(a*n2+b)*n3+c]=(float)v.real();
  }
}

static void build_cg(CGT* cg){
  float t000[1];  real_cg(0,0,0,t000); cg->c000=t000[0];
  real_cg(0,1,1,cg->c011);
  real_cg(1,0,1,cg->c101);
  real_cg(1,1,0,cg->c110);
  real_cg(1,1,1,cg->c111);
  real_cg(1,2,1,cg->c121);
}

// ---------------- device helpers ----------------
__device__ __forceinline__ float sspf(float x){
  return fmaxf(x,0.0f) + __logf(1.0f + __expf(-fabsf(x))) - 0.69314718055994530942f;
}

__device__ __forceinline__ float edge_env_inline(float d, float* emb){
#pragma unroll
  for(int k=0;k<10;k++){
    float t = d - (0.7f + (float)k*(1.0f/9.0f));
    emb[k] = __expf(-t*t*50.0f);
  }
  float u = d*(1.0f/1.5f);
  if(u >= 1.0f) return 0.0f;
  float u2=u*u, u3=u2*u, u6=u3*u3, u7=u6*u, u8=u7*u;
  return 1.0f - 28.0f*u6 + 48.0f*u7 - 21.0f*u8;
}

// ================= CSR build =================
__global__ void deg_kernel(const int* __restrict__ ei, int* __restrict__ deg, int E){
  int e = blockIdx.x*blockDim.x + threadIdx.x;
  if(e >= E) return;
  atomicAdd(&deg[ei[E+e]], 1);
}

__global__ void scanA_kernel(const int* __restrict__ deg, int* __restrict__ rowptr,
                             int* __restrict__ bsum, int N){
  __shared__ int sm[256];
  int t = threadIdx.x, b = blockIdx.x, i = b*256 + t;
  int v = (i < N) ? deg[i] : 0;
  sm[t] = v;
  __syncthreads();
  for(int off=1; off<256; off<<=1){
    int add = (t >= off) ? sm[t-off] : 0;
    __syncthreads();
    sm[t] += add;
    __syncthreads();
  }
  if(i < N) rowptr[i] = sm[t] - v;
  if(t == 255) bsum[b] = sm[255];
}

__global__ void scanB_kernel(int* __restrict__ bsum, int* __restrict__ rowptr, int nb, int N){
  __shared__ int sm[256];
  int t = threadIdx.x;
  int v = (t < nb) ? bsum[t] : 0;
  sm[t] = v;
  __syncthreads();
  for(int off=1; off<256; off<<=1){
    int add = (t >= off) ? sm[t-off] : 0;
    __syncthreads();
    sm[t] += add;
    __syncthreads();
  }
  if(t < nb) bsum[t] = sm[t] - v;
  if(t == 255) rowptr[N] = sm[255];
}

__global__ void scanC_kernel(int* __restrict__ rowptr, const int* __restrict__ bsum, int N){
  int i = blockIdx.x*blockDim.x + threadIdx.x;
  if(i < N) rowptr[i] += bsum[i>>8];
}

// record (3 float4 = 48B): {elen,src,sh0,sh1}{sh2..5}{sh6,sh7,sh8,0}
__global__ void fill_kernel(const int* __restrict__ ei, const float* __restrict__ elen,
                            const float* __restrict__ sh,
                            const int* __restrict__ rowptr, int* __restrict__ fillc,
                            float* __restrict__ pedge, int E){
  int e = blockIdx.x*blockDim.x + threadIdx.x;
  if(e >= E) return;
  int dst = ei[E+e];
  int p = atomicAdd(&fillc[dst], 1);
  size_t slot = (size_t)rowptr[dst] + p;
  const float* she = sh + (size_t)e*9;
  float4* pd = (float4*)pedge + slot*3;
  pd[0] = make_float4(elen[e], __int_as_float(ei[e]), she[0], she[1]);
  pd[1] = make_float4(she[2], she[3], she[4], she[5]);
  pd[2] = make_float4(she[6], she[7], she[8], 0.f);
}

// ================= gather layers =================
// Thread per (node, h); 64-thread blocks (1 wave = 2 nodes) to cut block-granularity
// load imbalance: a 256-thread block retires at the max degree of 8 nodes (~1.6x mean);
// a 64-thread block at the max of 2 (~1.2x). Loop body identical to round-5 best.

__global__ __launch_bounds__(64)
void g1_kernel(const float* __restrict__ x,
               const float* __restrict__ pedge,
               const int* __restrict__ rowptr,
               const float* __restrict__ W1, const float* __restrict__ b1,
               float* __restrict__ out, int N, CGT cg){
  int t = blockIdx.x*64 + threadIdx.x;
  int n = t >> 5, h = t & 31;
  if(n >= N) return;
  int beg = rowptr[n], end = rowptr[n+1];
  float bb0 = b1[h], bb1 = b1[HCH+h];
  float a0=0.f, a1=0.f, a2=0.f, a3=0.f;
  const float4* pe = (const float4*)pedge;
  for(int i=beg;i<end;i++){
    float4 r0 = pe[(size_t)i*3+0];
    float4 r1 = pe[(size_t)i*3+1];
    float em[10];
    float ew = edge_env_inline(r0.x, em);
    int src = __float_as_int(r0.y);
    float w0 = bb0, w1v = bb1;
#pragma unroll
    for(int k=0;k<10;k++){
      w0  += em[k]*W1[k*64 + h];
      w1v += em[k]*W1[k*64 + HCH + h];
    }
    float base = x[src]*ew;
    a0 += cg.c000*base*r0.z*w0;
    float bw = base*w1v;
    a1 += (cg.c011[0]*r0.w + cg.c011[3]*r1.x + cg.c011[6]*r1.y)*bw;
    a2 += (cg.c011[1]*r0.w + cg.c011[4]*r1.x + cg.c011[7]*r1.y)*bw;
    a3 += (cg.c011[2]*r0.w + cg.c011[5]*r1.x + cg.c011[8]*r1.y)*bw;
  }
  float ss = a1*a1 + a2*a2 + a3*a3 + 1e-12f;
  float rn = rsqrtf(ss);
  float sc = sspf(ss*rn)*rn;
  float* p = out + (size_t)n*128;
  p[h]       = sspf(a0);
  p[HCH+h]   = a1*sc;
  p[2*HCH+h] = a2*sc;
  p[3*HCH+h] = a3*sc;
}

__global__ __launch_bounds__(64)
void g2_kernel(const float* __restrict__ hin,
               const float* __restrict__ pedge,
               const int* __restrict__ rowptr,
               const float* __restrict__ W2, const float* __restrict__ b2,
               float* __restrict__ out, int N, CGT cg){
  int t = blockIdx.x*64 + threadIdx.x;
  int n = t >> 5, h = t & 31;
  if(n >= N) return;
  int beg = rowptr[n], end = rowptr[n+1];
  float bb[6];
#pragma unroll
  for(int p=0;p<6;p++) bb[p] = b2[p*HCH + h];
  float a0=0.f, a1=0.f, a2=0.f, a3=0.f;
  const float4* pe = (const float4*)pedge;
  for(int i=beg;i<end;i++){
    float4 r0 = pe[(size_t)i*3+0];
    float4 r1 = pe[(size_t)i*3+1];
    float4 r2 = pe[(size_t)i*3+2];
    float em[10];
    float ew = edge_env_inline(r0.x, em);
    int src = __float_as_int(r0.y);
    float w_[6];
#pragma unroll
    for(int p=0;p<6;p++) w_[p] = bb[p];
#pragma unroll
    for(int k=0;k<10;k++)
#pragma unroll
      for(int p=0;p<6;p++) w_[p] += em[k]*W2[k*192 + p*HCH + h];
    const float* hn = hin + (size_t)src*128;
    float x0  = hn[h];
    float xv0 = hn[HCH+h], xv1 = hn[2*HCH+h], xv2 = hn[3*HCH+h];
    float s0  = r0.z;
    float sv0 = r0.w, sv1 = r1.x, sv2 = r1.y;
    float s2v[5] = { r1.z, r1.w, r2.x, r2.y, r2.z };

    float m0 = 0.0f, m1 = 0.0f, m2 = 0.0f, m3 = 0.0f;
    m0 += cg.c000 * x0 * s0 * w_[0];
    {
      float xw = x0 * w_[1];
      m1 += (cg.c011[0]*sv0 + cg.c011[3]*sv1 + cg.c011[6]*sv2)*xw;
      m2 += (cg.c011[1]*sv0 + cg.c011[4]*sv1 + cg.c011[7]*sv2)*xw;
      m3 += (cg.c011[2]*sv0 + cg.c011[5]*sv1 + cg.c011[8]*sv2)*xw;
    }
    {
      float sw = s0 * w_[2];
      m1 += (cg.c101[0]*xv0 + cg.c101[3]*xv1 + cg.c101[6]*xv2)*sw;
      m2 += (cg.c101[1]*xv0 + cg.c101[4]*xv1 + cg.c101[7]*xv2)*sw;
      m3 += (cg.c101[2]*xv0 + cg.c101[5]*xv1 + cg.c101[8]*xv2)*sw;
    }
    {
      float tt = cg.c110[0]*xv0*sv0 + cg.c110[1]*xv0*sv1 + cg.c110[2]*xv0*sv2
               + cg.c110[3]*xv1*sv0 + cg.c110[4]*xv1*sv1 + cg.c110[5]*xv1*sv2
               + cg.c110[6]*xv2*sv0 + cg.c110[7]*xv2*sv1 + cg.c110[8]*xv2*sv2;
      m0 += tt * w_[3];
    }
    {
      float xvv[3] = {xv0, xv1, xv2};
      float svv[3] = {sv0, sv1, sv2};
      float t1=0.f, t2=0.f, t3=0.f;
#pragma unroll
      for(int a=0;a<3;a++)
#pragma unroll
        for(int b=0;b<3;b++){
          float xs = xvv[a]*svv[b];
          t1 += cg.c111[(a*3+b)*3+0]*xs;
          t2 += cg.c111[(a*3+b)*3+1]*xs;
          t3 += cg.c111[(a*3+b)*3+2]*xs;
        }
      m1 += t1*w_[4]; m2 += t2*w_[4]; m3 += t3*w_[4];
    }
    {
      float xvv[3] = {xv0, xv1, xv2};
      float t1=0.f, t2=0.f, t3=0.f;
#pragma unroll
      for(int a=0;a<3;a++)
#pragma unroll
        for(int b=0;b<5;b++){
          float xs = xvv[a]*s2v[b];
          t1 += cg.c121[(a*5+b)*3+0]*xs;
          t2 += cg.c121[(a*5+b)*3+1]*xs;
          t3 += cg.c121[(a*5+b)*3+2]*xs;
        }
      m1 += t1*w_[5]; m2 += t2*w_[5]; m3 += t3*w_[5];
    }
    a0 += m0*ew; a1 += m1*ew; a2 += m2*ew; a3 += m3*ew;
  }
  float ss = a1*a1 + a2*a2 + a3*a3 + 1e-12f;
  float rn = rsqrtf(ss);
  float sc = sspf(ss*rn)*rn;
  float* p = out + (size_t)n*128;
  p[h]       = sspf(a0);
  p[HCH+h]   = a1*sc;
  p[2*HCH+h] = a2*sc;
  p[3*HCH+h] = a3*sc;
}

__global__ __launch_bounds__(64)
void g3_kernel(const float* __restrict__ hin,
               const float* __restrict__ pedge,
               const int* __restrict__ rowptr,
               const int* __restrict__ batch,
               const float* __restrict__ W3, const float* __restrict__ b3,
               float* __restrict__ g, int N, CGT cg){
  int t = blockIdx.x*64 + threadIdx.x;
  int n = t >> 5, h = t & 31;
  if(n >= N) return;
  int beg = rowptr[n], end = rowptr[n+1];
  float bb0 = b3[h], bb1 = b3[HCH+h];
  float acc = 0.f;
  const float4* pe = (const float4*)pedge;
  for(int i=beg;i<end;i++){
    float4 r0 = pe[(size_t)i*3+0];
    float4 r1 = pe[(size_t)i*3+1];
    float em[10];
    float ew = edge_env_inline(r0.x, em);
    int src = __float_as_int(r0.y);
    float w0 = bb0, w1v = bb1;
#pragma unroll
    for(int k=0;k<10;k++){
      w0  += em[k]*W3[k*64 + h];
      w1v += em[k]*W3[k*64 + HCH + h];
    }
    const float* hn = hin + (size_t)src*128;
    float x0 = hn[h];
    float xv0 = hn[HCH+h], xv1 = hn[2*HCH+h], xv2 = hn[3*HCH+h];
    float m = cg.c000 * x0 * r0.z * w0;
    float tt = cg.c110[0]*xv0*r0.w + cg.c110[1]*xv0*r1.x + cg.c110[2]*xv0*r1.y
             + cg.c110[3]*xv1*r0.w + cg.c110[4]*xv1*r1.x + cg.c110[5]*xv1*r1.y
             + cg.c110[6]*xv2*r0.w + cg.c110[7]*xv2*r1.x + cg.c110[8]*xv2*r1.y;
    m += tt * w1v;
    acc += m*ew;
  }
  float si = acc*__frcp_rn(1.0f + __expf(-acc));
  atomicAdd(&g[(size_t)batch[n]*HCH + h], si);
}

// ================= fallback atomic-scatter layers =================
__global__ void l1_kernel(const float* __restrict__ x, const int* __restrict__ ei,
                          const float* __restrict__ sh, const float* __restrict__ elen,
                          const float* __restrict__ W1, const float* __restrict__ b1,
                          float* __restrict__ acc, int E, CGT cg){
  int t = blockIdx.x*blockDim.x + threadIdx.x;
  int e = t >> 5, h = t & 31;
  if(e >= E) return;
  float emb[10];
  float ew = edge_env_inline(elen[e], emb);
  int src = ei[e], dst = ei[E+e];
  float w0 = b1[h], w1v = b1[HCH+h];
#pragma unroll
  for(int k=0;k<10;k++){
    w0  += emb[k]*W1[k*64 + h];
    w1v += emb[k]*W1[k*64 + HCH + h];
  }
  const float* she = sh + (size_t)e*9;
  float base = x[src]*ew;
  float* ad = acc + (size_t)dst*128;
  atomicAdd(&ad[h], cg.c000*base*she[0]*w0);
  float bw = base*w1v;
  atomicAdd(&ad[HCH+h],   (cg.c011[0]*she[1] + cg.c011[3]*she[2] + cg.c011[6]*she[3])*bw);
  atomicAdd(&ad[2*HCH+h], (cg.c011[1]*she[1] + cg.c011[4]*she[2] + cg.c011[7]*she[3])*bw);
  atomicAdd(&ad[3*HCH+h], (cg.c011[2]*she[1] + cg.c011[5]*she[2] + cg.c011[8]*she[3])*bw);
}

__global__ void normact_kernel(float* __restrict__ buf, int N){
  int t = blockIdx.x*blockDim.x + threadIdx.x;
  int n = t >> 5, h = t & 31;
  if(n >= N) return;
  float* p = buf + (size_t)n*128;
  float s  = p[h];
  float v1 = p[HCH+h], v2 = p[2*HCH+h], v3 = p[3*HCH+h];
  float ss = v1*v1 + v2*v2 + v3*v3 + 1e-12f;
  float rn = rsqrtf(ss);
  float sc = sspf(ss*rn)*rn;
  p[h]       = sspf(s);
  p[HCH+h]   = v1*sc;
  p[2*HCH+h] = v2*sc;
  p[3*HCH+h] = v3*sc;
}

__global__ void l2_kernel(const float* __restrict__ hin, const int* __restrict__ ei,
                          const float* __restrict__ sh, const float* __restrict__ elen,
                          const float* __restrict__ W2, const float* __restrict__ b2,
                          float* __restrict__ acc, int E, CGT cg){
  int t = blockIdx.x*blockDim.x + threadIdx.x;
  int e = t >> 5, h = t & 31;
  if(e >= E) return;
  float emb[10];
  float ew = edge_env_inline(elen[e], emb);
  int src = ei[e], dst = ei[E+e];
  float w[6];
#pragma unroll
  for(int p=0;p<6;p++) w[p] = b2[p*HCH + h];
#pragma unroll
  for(int k=0;k<10;k++){
    float ek = emb[k];
    const float* Wr = W2 + k*192;
#pragma unroll
    for(int p=0;p<6;p++) w[p] += ek*Wr[p*HCH + h];
  }
  const float* hn = hin + (size_t)src*128;
  float x0 = hn[h];
  float xv[3] = { hn[HCH+h], hn[2*HCH+h], hn[3*HCH+h] };
  const float* she = sh + (size_t)e*9;
  float s0 = she[0];
  float sv[3]  = { she[1], she[2], she[3] };
  float s2v[5] = { she[4], she[5], she[6], she[7], she[8] };
  float m0 = 0.0f, m[3] = {0.0f,0.0f,0.0f};
  m0 += cg.c000 * x0 * s0 * w[0];
#pragma unroll
  for(int c=0;c<3;c++){
    float tc = cg.c011[0*3+c]*sv[0] + cg.c011[1*3+c]*sv[1] + cg.c011[2*3+c]*sv[2];
    m[c] += tc * x0 * w[1];
  }
#pragma unroll
  for(int c=0;c<3;c++){
    float tc = cg.c101[0*3+c]*xv[0] + cg.c101[1*3+c]*xv[1] + cg.c101[2*3+c]*xv[2];
    m[c] += tc * s0 * w[2];
  }
  {
    float tt=0.0f;
#pragma unroll
    for(int a=0;a<3;a++)
#pragma unroll
      for(int b=0;b<3;b++) tt += cg.c110[a*3+b]*xv[a]*sv[b];
    m0 += tt * w[3];
  }
#pragma unroll
  for(int c=0;c<3;c++){
    float tt=0.0f;
#pragma unroll
    for(int a=0;a<3;a++)
#pragma unroll
      for(int b=0;b<3;b++) tt += cg.c111[(a*3+b)*3+c]*xv[a]*sv[b];
    m[c] += tt * w[4];
  }
#pragma unroll
  for(int c=0;c<3;c++){
    float tt=0.0f;
#pragma unroll
    for(int a=0;a<3;a++)
#pragma unroll
      for(int b=0;b<5;b++) tt += cg.c121[(a*5+b)*3+c]*xv[a]*s2v[b];
    m[c] += tt * w[5];
  }
  float* ad = acc + (size_t)dst*128;
  atomicAdd(&ad[h], m0*ew);
#pragma unroll
  for(int c=0;c<3;c++) atomicAdd(&ad[(1+c)*HCH + h], m[c]*ew);
}

__global__ void l3_kernel(const float* __restrict__ hin, const int* __restrict__ ei,
                          const float* __restrict__ sh, const float* __restrict__ elen,
                          const float* __restrict__ W3, const float* __restrict__ b3,
                          float* __restrict__ acc, int E, CGT cg){
  int t = blockIdx.x*blockDim.x + threadIdx.x;
  int e = t >> 5, h = t & 31;
  if(e >= E) return;
  float emb[10];
  float ew = edge_env_inline(elen[e], emb);
  int src = ei[e], dst = ei[E+e];
  float w0 = b3[h], w1v = b3[HCH+h];
#pragma unroll
  for(int k=0;k<10;k++){
    w0  += emb[k]*W3[k*64 + h];
    w1v += emb[k]*W3[k*64 + HCH + h];
  }
  const float* hn = hin + (size_t)src*128;
  float x0 = hn[h];
  float xv[3] = { hn[HCH+h], hn[2*HCH+h], hn[3*HCH+h] };
  const float* she = sh + (size_t)e*9;
  float m = cg.c000 * x0 * she[0] * w0;
  float tt = cg.c110[0]*xv[0]*she[1] + cg.c110[1]*xv[0]*she[2] + cg.c110[2]*xv[0]*she[3]
           + cg.c110[3]*xv[1]*she[1] + cg.c110[4]*xv[1]*she[2] + cg.c110[5]*xv[1]*she[3]
           + cg.c110[6]*xv[2]*she[1] + cg.c110[7]*xv[2]*she[2] + cg.c110[8]*xv[2]*she[3];
  m += tt * w1v;
  atomicAdd(&acc[(size_t)dst*HCH + h], m*ew);
}

__global__ void pool_kernel(const float* __restrict__ acc, const int* __restrict__ batch,
                            float* __restrict__ g, int N){
  int t = blockIdx.x*blockDim.x + threadIdx.x;
  int n = t >> 5, h = t & 31;
  if(n >= N) return;
  float v = acc[(size_t)n*HCH + h];
  float si = v*__frcp_rn(1.0f + __expf(-v));
  atomicAdd(&g[(size_t)batch[n]*HCH + h], si);
}

// ---------------- head ----------------
__global__ void head_kernel(const float* __restrict__ g, const float* __restrict__ Wo,
                            const float* __restrict__ bo, float* __restrict__ out){
  int gi = threadIdx.x;
  if(gi >= 128) return;
  float logit[8];
#pragma unroll
  for(int o=0;o<8;o++) logit[o] = bo[o];
  for(int hh=0; hh<HCH; hh++){
    float gv = g[gi*HCH + hh];
#pragma unroll
    for(int o=0;o<8;o++) logit[o] += gv*Wo[hh*8 + o];
  }
  float mx = logit[0];
#pragma unroll
  for(int o=1;o<8;o++) mx = fmaxf(mx, logit[o]);
  float ex[8]; float s=0.0f;
#pragma unroll
  for(int o=0;o<8;o++){ ex[o]=__expf(logit[o]-mx); s+=ex[o]; }
  float inv = 1.0f/s;
#pragma unroll
  for(int o=0;o<8;o++) out[gi*8 + o] = ex[o]*inv;
}

extern "C" void kernel_launch(void* const* d_in, const int* in_sizes, int n_in,
                              void* d_out, int out_size, void* d_ws, size_t ws_size,
                              hipStream_t stream){
  const float* x    = (const float*)d_in[0];
  const int*   ei   = (const int*)  d_in[1];
  const float* sh   = (const float*)d_in[2];
  const float* elen = (const float*)d_in[3];
  const int*   batch= (const int*)  d_in[4];
  const float* W1   = (const float*)d_in[5];
  const float* b1   = (const float*)d_in[6];
  const float* W2   = (const float*)d_in[7];
  const float* b2   = (const float*)d_in[8];
  const float* W3   = (const float*)d_in[9];
  const float* b3   = (const float*)d_in[10];
  const float* Wo   = (const float*)d_in[11];
  const float* bo   = (const float*)d_in[12];
  int N = in_sizes[0];
  int E = in_sizes[3];

  CGT cg; build_cg(&cg);

  int nb = (N + 255)/256;

  // CSR-path workspace layout
  float* pedge  = (float*)d_ws;                    // E*12 floats (48B records)
  float* bufA   = pedge + (size_t)E*12;            // N*128
  float* bufB   = bufA + (size_t)N*128;            // N*128
  float* g      = bufB + (size_t)N*128;            // 128*32
  int*   deg    = (int*)(g + 128*HCH);             // N
  int*   fillc  = deg + N;                         // N
  int*   rowptr = fillc + N;                       // N+1
  int*   bsum   = rowptr + (N+1);                  // <=256

  size_t csr_b = ((size_t)E*12 + (size_t)N*128*2 + 128*HCH)*sizeof(float)
               + ((size_t)3*N + 1 + 256)*sizeof(int);
  bool use_csr = (ws_size >= csr_b) && (nb <= 256);

  dim3 blk(256);
  dim3 blk64(64);
  int eblk1   = (E + 255)/256;
  int eblocks = (int)(((long long)E*HCH + 255)/256);
  int nblocks = (int)(((long long)N*HCH + 255)/256);
  int wblocks = (int)(((long long)N*HCH + 63)/64);    // 64-thread blocks for gathers

  if(use_csr){
    hipMemsetAsync(g, 0, (size_t)(128*HCH)*sizeof(float) + (size_t)2*N*sizeof(int), stream);
    deg_kernel <<<eblk1, blk, 0, stream>>>(ei, deg, E);
    scanA_kernel<<<nb, blk, 0, stream>>>(deg, rowptr, bsum, N);
    scanB_kernel<<<1, blk, 0, stream>>>(bsum, rowptr, nb, N);
    scanC_kernel<<<nb, blk, 0, stream>>>(rowptr, bsum, N);
    fill_kernel<<<eblk1, blk, 0, stream>>>(ei, elen, sh, rowptr, fillc, pedge, E);
    g1_kernel<<<wblocks, blk64, 0, stream>>>(x, pedge, rowptr, W1, b1, bufA, N, cg);
    g2_kernel<<<wblocks, blk64, 0, stream>>>(bufA, pedge, rowptr, W2, b2, bufB, N, cg);
    g3_kernel<<<wblocks, blk64, 0, stream>>>(bufB, pedge, rowptr, batch, W3, b3, g, N, cg);
    head_kernel<<<1, 128, 0, stream>>>(g, Wo, bo, (float*)d_out);
  } else {
    float* fbufA = (float*)d_ws;
    float* fbufB = fbufA + (size_t)N*128;
    float* fbufC = fbufB + (size_t)N*128;
    float* fg    = fbufC + (size_t)N*HCH;
    size_t base_b = ((size_t)N*128*2 + (size_t)N*HCH + 128*HCH)*sizeof(float);
    hipMemsetAsync(d_ws, 0, base_b, stream);
    l1_kernel<<<eblocks, blk, 0, stream>>>(x, ei, sh, elen, W1, b1, fbufA, E, cg);
    normact_kernel<<<nblocks, blk, 0, stream>>>(fbufA, N);
    l2_kernel<<<eblocks, blk, 0, stream>>>(fbufA, ei, sh, elen, W2, b2, fbufB, E, cg);
    normact_kernel<<<nblocks, blk, 0, stream>>>(fbufB, N);
    l3_kernel<<<eblocks, blk, 0, stream>>>(fbufB, ei, sh, elen, W3, b3, fbufC, E, cg);
    pool_kernel<<<nblocks, blk, 0, stream>>>(fbufC, batch, fg, N);
    head_kernel<<<1, 128, 0, stream>>>(fg, Wo, bo, (float*)d_out);
  }
}